// Round 11
// baseline (181.514 us; speedup 1.0000x reference)
//
#include <hip/hip_runtime.h>

// Flash attention, non-causal: O = softmax(Q K^T / sqrt(64)) V
// B=64, S=2048, D=64, fp32 in/out, bf16 MFMA compute (fp32 accum).
//
// R20 = R19 (92.3us, fat waves verified) + KVBLK=64 + strip pipeline.
// R19 post-mortem: derived counters are per-CU-summed (gfx94x fallback)
// -- real per-SIMD pipe occupancy is MFMA ~8%, VALU ~9%. Nothing is
// saturated; the kernel is ~70% latency/barrier-stalled (R18 41% occ ==
// R19 20% occ == same perf proves TLP isn't binding either). So: halve
// barrier count (KVBLK 32->64, R14's byte-verified staging) and overlap
// pipes WITHIN a wave: QK0 -> SM0 -> QK1 (z reassigned, single live
// range -- the multi-live-z formulation is the only delta correlated
// with R15/R16 NaNs) -> PV0 interleaved with SM1 -> PV1. SM1's exp2/pk2
// (VALU/trans) hides under PV0's MFMAs. All named regs (no f32x16
// arrays), all layout algebra byte-identical to verified R14/R19.
// Spill tripwire: WRITE_SIZE must stay exactly 32768 KB.

typedef short bf16x8 __attribute__((ext_vector_type(8)));
typedef float f32x16 __attribute__((ext_vector_type(16)));

#define SQK 0.18033688011112042f /* (1/8) * log2(e) : softmax in exp2 domain */

__device__ __forceinline__ short f2bf(float x) {
  unsigned u = __float_as_uint(x);
  u = (u + 0x7fffu + ((u >> 16) & 1u)) >> 16;  // RNE (one-time Q conv only)
  return (short)u;
}

// pack two floats to bf16x2 in ONE instruction (RNE): lo -> [15:0], hi -> [31:16]
__device__ __forceinline__ unsigned pk2(float lo, float hi) {
  unsigned r;
  asm("v_cvt_pk_bf16_f32 %0, %1, %2" : "=v"(r) : "v"(lo), "v"(hi));
  return r;
}

// exp2 one 8-score half of z (offset OFF), accumulate rowsum into RS,
// emit packed bf16x8 A-fragment into PUV. Keys of element i:
// base + (i&3) + 8*(i>>2) + 4*hi -- matches vsh's permuted columns.
#define SM_HALF(ZV, OFF, RS, PUV)                                        \
  {                                                                      \
    float e0 = __builtin_amdgcn_exp2f(ZV[OFF + 0]);                      \
    float e1 = __builtin_amdgcn_exp2f(ZV[OFF + 1]);                      \
    float e2 = __builtin_amdgcn_exp2f(ZV[OFF + 2]);                      \
    float e3 = __builtin_amdgcn_exp2f(ZV[OFF + 3]);                      \
    float e4 = __builtin_amdgcn_exp2f(ZV[OFF + 4]);                      \
    float e5 = __builtin_amdgcn_exp2f(ZV[OFF + 5]);                      \
    float e6 = __builtin_amdgcn_exp2f(ZV[OFF + 6]);                      \
    float e7 = __builtin_amdgcn_exp2f(ZV[OFF + 7]);                      \
    RS += ((e0 + e1) + (e2 + e3)) + ((e4 + e5) + (e6 + e7));             \
    union { bf16x8 v; unsigned u[4]; } pu_;                              \
    pu_.u[0] = pk2(e0, e1); pu_.u[1] = pk2(e2, e3);                      \
    pu_.u[2] = pk2(e4, e5); pu_.u[3] = pk2(e6, e7);                      \
    PUV = pu_.v;                                                         \
  }

__global__ __launch_bounds__(512, 2) void DotProductAttention_44573170598739_kernel(
    const float* __restrict__ Q, const float* __restrict__ K,
    const float* __restrict__ V, float* __restrict__ O) {
  constexpr int S = 2048, D = 64;
  const int b   = blockIdx.x;                // batch (XCD-locality swizzle)
  const int q0  = blockIdx.y * 512;          // block's first q row
  const int tid = threadIdx.x;
  const int w    = tid >> 6;                 // wave 0..7, owns 64 q rows
  const int lane = tid & 63;
  const int hi   = lane >> 5;                // half-wave 0/1
  const int r32  = lane & 31;

  // double-buffered tiles, KVBLK = 64 keys (R14 layout, verified)
  __shared__ __align__(16) short ksh[2][64 * 72];  // K tile, row-major [key][d]
  __shared__ __align__(16) short vsh[2][64 * 72];  // V tile, [d][key-col], cols
                                                   // permuted within each 16-key
                                                   // block: col = (k&3)|((k&4)<<1)|((k&8)>>1)

  // ---- Q fragments, both strips (regs, whole kernel), exp2-domain scaled.
  // qf{s}[dd] = Q[q = q0 + w*64 + s*32 + r32][d = 16dd + 8hi + j]
  bf16x8 qf0[4], qf1[4];
#pragma unroll
  for (int dd = 0; dd < 4; ++dd) {
    const float* qp = Q + ((size_t)b * S + q0 + w * 64 + r32) * D + dd * 16 + hi * 8;
    float4 x = ((const float4*)qp)[0];
    float4 y = ((const float4*)qp)[1];
    bf16x8 f;
    f[0] = f2bf(x.x * SQK); f[1] = f2bf(x.y * SQK);
    f[2] = f2bf(x.z * SQK); f[3] = f2bf(x.w * SQK);
    f[4] = f2bf(y.x * SQK); f[5] = f2bf(y.y * SQK);
    f[6] = f2bf(y.z * SQK); f[7] = f2bf(y.w * SQK);
    qf0[dd] = f;
  }
#pragma unroll
  for (int dd = 0; dd < 4; ++dd) {
    const float* qp = Q + ((size_t)b * S + q0 + w * 64 + 32 + r32) * D + dd * 16 + hi * 8;
    float4 x = ((const float4*)qp)[0];
    float4 y = ((const float4*)qp)[1];
    bf16x8 f;
    f[0] = f2bf(x.x * SQK); f[1] = f2bf(x.y * SQK);
    f[2] = f2bf(x.z * SQK); f[3] = f2bf(x.w * SQK);
    f[4] = f2bf(y.x * SQK); f[5] = f2bf(y.y * SQK);
    f[6] = f2bf(y.z * SQK); f[7] = f2bf(y.w * SQK);
    qf1[dd] = f;
  }

  // O accumulators, NAMED (no f32x16 arrays anywhere).
  // oa{s}{dhalf}: D[row=q(16 rows)][col = d = 32*dhalf + r32]
  f32x16 oa00 = {}, oa01 = {}, oa10 = {}, oa11 = {};
  float rs0 = 0.f, rs1 = 0.f;  // per-strip lane share of rowsum[q = r32]
  const f32x16 z16c = {};      // persistent zero C-operand (never written)

  const float* Kb = K + (size_t)b * S * D;
  const float* Vb = V + (size_t)b * S * D;

  // V staging (R14, verified): wave w holds keys w*8+0..7 = 16-block (w>>1),
  // sub-half (w&1). Permuted cols: j<4 -> 4*(w&1)+j ; j>=4 -> 8+4*(w&1)+(j-4).
  const int vcb = 16 * (w >> 1) + 4 * (w & 1);

  float4 kx[2];
  float  vv[8];

  // ---- prologue: tile 0 -> buf0; tile 1 loads left in flight (R14 verbatim)
#pragma unroll
  for (int i = 0; i < 2; ++i)
    kx[i] = ((const float4*)Kb)[tid + 512 * i];
#pragma unroll
  for (int j = 0; j < 8; ++j)
    vv[j] = Vb[(w * 8 + j) * D + lane];
#pragma unroll
  for (int i = 0; i < 2; ++i) {
    int f = 4 * tid + 2048 * i;
    int row = f >> 6, col = f & 63;
    uint2 pk = { pk2(kx[i].x, kx[i].y), pk2(kx[i].z, kx[i].w) };
    *(uint2*)&ksh[0][row * 72 + col] = pk;
  }
  {
    uint2 plo = { pk2(vv[0], vv[1]), pk2(vv[2], vv[3]) };
    uint2 phi = { pk2(vv[4], vv[5]), pk2(vv[6], vv[7]) };
    *(uint2*)&vsh[0][lane * 72 + vcb]     = plo;
    *(uint2*)&vsh[0][lane * 72 + vcb + 8] = phi;
  }
#pragma unroll
  for (int i = 0; i < 2; ++i)
    kx[i] = ((const float4*)(Kb + 64 * D))[tid + 512 * i];
#pragma unroll
  for (int j = 0; j < 8; ++j)
    vv[j] = Vb[(64 + w * 8 + j) * D + lane];
  __syncthreads();

  int p = 0;
  for (int kt = 0; kt < S; kt += 64, p ^= 1) {
    // ---- stage tile kt+64 (regs from last iter) into buf p^1, then issue
    // loads for tile kt+128. buf[p^1] reads finished before last barrier.
    if (kt + 64 < S) {
#pragma unroll
      for (int i = 0; i < 2; ++i) {
        int f = 4 * tid + 2048 * i;
        int row = f >> 6, col = f & 63;
        uint2 pk = { pk2(kx[i].x, kx[i].y), pk2(kx[i].z, kx[i].w) };
        *(uint2*)&ksh[p ^ 1][row * 72 + col] = pk;
      }
      {
        uint2 plo = { pk2(vv[0], vv[1]), pk2(vv[2], vv[3]) };
        uint2 phi = { pk2(vv[4], vv[5]), pk2(vv[6], vv[7]) };
        *(uint2*)&vsh[p ^ 1][lane * 72 + vcb]     = plo;
        *(uint2*)&vsh[p ^ 1][lane * 72 + vcb + 8] = phi;
      }
      if (kt + 128 < S) {
        const float* Kg2 = Kb + (size_t)(kt + 128) * D;
        const float* Vg2 = Vb + (size_t)(kt + 128) * D;
#pragma unroll
        for (int i = 0; i < 2; ++i)
          kx[i] = ((const float4*)Kg2)[tid + 512 * i];
#pragma unroll
        for (int j = 0; j < 8; ++j)
          vv[j] = Vg2[(w * 8 + j) * D + lane];
      }
    }

    const short* kshp = ksh[p];
    const short* vshp = vsh[p];
#pragma unroll
    for (int t = 0; t < 2; ++t) {
      // K fragments (A-operand), shared by BOTH strips:
      // kf[dd] = K[key = 32t + r32][d = 16dd + 8hi + j]
      bf16x8 kf[4];
#pragma unroll
      for (int dd = 0; dd < 4; ++dd)
        kf[dd] = *(const bf16x8*)&kshp[(t * 32 + r32) * 72 + dd * 16 + hi * 8];

      // V fragments (B-operand), shared by BOTH strips:
      // vf{h}{dhalf} = V[key = 32t + 16h + perm(j) + 8hi][d = 32*dhalf + r32]
      bf16x8 vf00 = *(const bf16x8*)&vshp[r32 * 72 + t * 32 + hi * 8];
      bf16x8 vf01 = *(const bf16x8*)&vshp[(32 + r32) * 72 + t * 32 + hi * 8];
      bf16x8 vf10 = *(const bf16x8*)&vshp[r32 * 72 + t * 32 + 16 + hi * 8];
      bf16x8 vf11 = *(const bf16x8*)&vshp[(32 + r32) * 72 + t * 32 + 16 + hi * 8];

      // ---- strip0 QK (z live range #1)
      __builtin_amdgcn_s_setprio(1);
      f32x16 z = __builtin_amdgcn_mfma_f32_32x32x16_bf16(kf[0], qf0[0], z16c, 0, 0, 0);
      z = __builtin_amdgcn_mfma_f32_32x32x16_bf16(kf[1], qf0[1], z, 0, 0, 0);
      z = __builtin_amdgcn_mfma_f32_32x32x16_bf16(kf[2], qf0[2], z, 0, 0, 0);
      z = __builtin_amdgcn_mfma_f32_32x32x16_bf16(kf[3], qf0[3], z, 0, 0, 0);
      __builtin_amdgcn_s_setprio(0);

      // ---- strip0 softmax, both halves (pa0a/pa0b live across QK1)
      bf16x8 pa0a, pa0b;
      SM_HALF(z, 0, rs0, pa0a);
      SM_HALF(z, 8, rs0, pa0b);

      // ---- strip1 QK (z reassigned: single live range at a time)
      __builtin_amdgcn_s_setprio(1);
      z = __builtin_amdgcn_mfma_f32_32x32x16_bf16(kf[0], qf1[0], z16c, 0, 0, 0);
      z = __builtin_amdgcn_mfma_f32_32x32x16_bf16(kf[1], qf1[1], z, 0, 0, 0);
      z = __builtin_amdgcn_mfma_f32_32x32x16_bf16(kf[2], qf1[2], z, 0, 0, 0);
      z = __builtin_amdgcn_mfma_f32_32x32x16_bf16(kf[3], qf1[3], z, 0, 0, 0);
      __builtin_amdgcn_s_setprio(0);

      // ---- PV0 interleaved with strip1 softmax: SM1's exp2/pk2 (VALU +
      // trans pipes) hides under PV0's MFMAs (matrix pipe).
      bf16x8 pa1a, pa1b;
      __builtin_amdgcn_s_setprio(1);
      oa00 = __builtin_amdgcn_mfma_f32_32x32x16_bf16(pa0a, vf00, oa00, 0, 0, 0);
      oa01 = __builtin_amdgcn_mfma_f32_32x32x16_bf16(pa0a, vf01, oa01, 0, 0, 0);
      __builtin_amdgcn_s_setprio(0);
      SM_HALF(z, 0, rs1, pa1a);
      __builtin_amdgcn_s_setprio(1);
      oa00 = __builtin_amdgcn_mfma_f32_32x32x16_bf16(pa0b, vf10, oa00, 0, 0, 0);
      oa01 = __builtin_amdgcn_mfma_f32_32x32x16_bf16(pa0b, vf11, oa01, 0, 0, 0);
      __builtin_amdgcn_s_setprio(0);
      SM_HALF(z, 8, rs1, pa1b);

      // ---- PV1
      __builtin_amdgcn_s_setprio(1);
      oa10 = __builtin_amdgcn_mfma_f32_32x32x16_bf16(pa1a, vf00, oa10, 0, 0, 0);
      oa11 = __builtin_amdgcn_mfma_f32_32x32x16_bf16(pa1a, vf01, oa11, 0, 0, 0);
      oa10 = __builtin_amdgcn_mfma_f32_32x32x16_bf16(pa1b, vf10, oa10, 0, 0, 0);
      oa11 = __builtin_amdgcn_mfma_f32_32x32x16_bf16(pa1b, vf11, oa11, 0, 0, 0);
      __builtin_amdgcn_s_setprio(0);
    }
    __syncthreads();
  }

  // ---- epilogue, per strip: rowsum for q=r32 (combine hi halves), then
  // gather via one-time shfls. Row g of oa** is q-offset (g&3)+8(g>>2)+4hi.
  {
    float tot = rs0 + __shfl_xor(rs0, 32);
#pragma unroll
    for (int g = 0; g < 16; ++g) {
      int rq = (g & 3) + 8 * (g >> 2) + 4 * hi;
      float inv = 1.0f / __shfl(tot, rq);
      int q = q0 + w * 64 + rq;
      float* op = O + ((size_t)b * S + q) * D + r32;
      op[0]  = oa00[g] * inv;
      op[32] = oa01[g] * inv;
    }
  }
  {
    float tot = rs1 + __shfl_xor(rs1, 32);
#pragma unroll
    for (int g = 0; g < 16; ++g) {
      int rq = (g & 3) + 8 * (g >> 2) + 4 * hi;
      float inv = 1.0f / __shfl(tot, rq);
      int q = q0 + w * 64 + 32 + rq;
      float* op = O + ((size_t)b * S + q) * D + r32;
      op[0]  = oa10[g] * inv;
      op[32] = oa11[g] * inv;
    }
  }
}

extern "C" void kernel_launch(void* const* d_in, const int* in_sizes, int n_in,
                              void* d_out, int out_size, void* d_ws, size_t ws_size,
                              hipStream_t stream) {
  (void)in_sizes; (void)n_in; (void)out_size; (void)d_ws; (void)ws_size;
  const float* Q = (const float*)d_in[0];
  const float* K = (const float*)d_in[1];
  const float* V = (const float*)d_in[2];
  float* O = (float*)d_out;
  // grid.x = batch: linear block id = x + 64*y -> XCD = id%8 = b%8, so all
  // 4 q-blocks of a batch share one XCD (K/V L2 reuse). 256 blocks = 1/CU.
  dim3 grid(64, 2048 / 512, 1);
  dim3 block(512, 1, 1);
  hipLaunchKernelGGL(DotProductAttention_44573170598739_kernel,
                     grid, block, 0, stream, Q, K, V, O);
}

// Round 13
// 172.545 us; speedup vs baseline: 1.0520x; 1.0520x over previous
//
#include <hip/hip_runtime.h>

// Flash attention, non-causal: O = softmax(Q K^T / sqrt(64)) V
// B=64, S=2048, D=64, fp32 in/out, bf16 MFMA compute (fp32 accum).
//
// R21 = R20 (90.4us) with ALL s_setprio deleted. Single-variable test.
// (Resubmit: previous round was an infra failure, no data.)
// Plateau evidence: R14/R18/R19/R20 (16 vs 8 waves/CU, 32 vs 64 q/wave,
// KVBLK 32/64, pipelined or not) all land 90-92us at MfmaUtil ~31%
// (= 27.6us MFMA floor / 90us wall -- self-consistent). No pipe is near
// saturation; the limiter is scheduling. Shared mechanism in every
// variant: the setprio blanket. With 2 barrier-locked waves/SIMD, wave A
// at prio 1 (MFMA cluster, ~128cy matrix-pipe occupancy) STARVES co-wave
// B's prio-0 softmax/LDS work -- precisely what must hide under A's
// MFMAs. B's next cluster is late -> pipe gap. This is m190's measured
// anti-pattern (setprio hurts co-barrier'd GEMM waves); the m191 win was
// independent 1-wave blocks, not our case. Everything else byte-identical
// to R20 (verified). Spill tripwire: WRITE_SIZE must stay 32768 KB.

typedef short bf16x8 __attribute__((ext_vector_type(8)));
typedef float f32x16 __attribute__((ext_vector_type(16)));

#define SQK 0.18033688011112042f /* (1/8) * log2(e) : softmax in exp2 domain */

__device__ __forceinline__ short f2bf(float x) {
  unsigned u = __float_as_uint(x);
  u = (u + 0x7fffu + ((u >> 16) & 1u)) >> 16;  // RNE (one-time Q conv only)
  return (short)u;
}

// pack two floats to bf16x2 in ONE instruction (RNE): lo -> [15:0], hi -> [31:16]
__device__ __forceinline__ unsigned pk2(float lo, float hi) {
  unsigned r;
  asm("v_cvt_pk_bf16_f32 %0, %1, %2" : "=v"(r) : "v"(lo), "v"(hi));
  return r;
}

// exp2 one 8-score half of z (offset OFF), accumulate rowsum into RS,
// emit packed bf16x8 A-fragment into PUV. Keys of element i:
// base + (i&3) + 8*(i>>2) + 4*hi -- matches vsh's permuted columns.
#define SM_HALF(ZV, OFF, RS, PUV)                                        \
  {                                                                      \
    float e0 = __builtin_amdgcn_exp2f(ZV[OFF + 0]);                      \
    float e1 = __builtin_amdgcn_exp2f(ZV[OFF + 1]);                      \
    float e2 = __builtin_amdgcn_exp2f(ZV[OFF + 2]);                      \
    float e3 = __builtin_amdgcn_exp2f(ZV[OFF + 3]);                      \
    float e4 = __builtin_amdgcn_exp2f(ZV[OFF + 4]);                      \
    float e5 = __builtin_amdgcn_exp2f(ZV[OFF + 5]);                      \
    float e6 = __builtin_amdgcn_exp2f(ZV[OFF + 6]);                      \
    float e7 = __builtin_amdgcn_exp2f(ZV[OFF + 7]);                      \
    RS += ((e0 + e1) + (e2 + e3)) + ((e4 + e5) + (e6 + e7));             \
    union { bf16x8 v; unsigned u[4]; } pu_;                              \
    pu_.u[0] = pk2(e0, e1); pu_.u[1] = pk2(e2, e3);                      \
    pu_.u[2] = pk2(e4, e5); pu_.u[3] = pk2(e6, e7);                      \
    PUV = pu_.v;                                                         \
  }

__global__ __launch_bounds__(512, 2) void DotProductAttention_44573170598739_kernel(
    const float* __restrict__ Q, const float* __restrict__ K,
    const float* __restrict__ V, float* __restrict__ O) {
  constexpr int S = 2048, D = 64;
  const int b   = blockIdx.x;                // batch (XCD-locality swizzle)
  const int q0  = blockIdx.y * 512;          // block's first q row
  const int tid = threadIdx.x;
  const int w    = tid >> 6;                 // wave 0..7, owns 64 q rows
  const int lane = tid & 63;
  const int hi   = lane >> 5;                // half-wave 0/1
  const int r32  = lane & 31;

  // double-buffered tiles, KVBLK = 64 keys (R14 layout, verified)
  __shared__ __align__(16) short ksh[2][64 * 72];  // K tile, row-major [key][d]
  __shared__ __align__(16) short vsh[2][64 * 72];  // V tile, [d][key-col], cols
                                                   // permuted within each 16-key
                                                   // block: col = (k&3)|((k&4)<<1)|((k&8)>>1)

  // ---- Q fragments, both strips (regs, whole kernel), exp2-domain scaled.
  // qf{s}[dd] = Q[q = q0 + w*64 + s*32 + r32][d = 16dd + 8hi + j]
  bf16x8 qf0[4], qf1[4];
#pragma unroll
  for (int dd = 0; dd < 4; ++dd) {
    const float* qp = Q + ((size_t)b * S + q0 + w * 64 + r32) * D + dd * 16 + hi * 8;
    float4 x = ((const float4*)qp)[0];
    float4 y = ((const float4*)qp)[1];
    bf16x8 f;
    f[0] = f2bf(x.x * SQK); f[1] = f2bf(x.y * SQK);
    f[2] = f2bf(x.z * SQK); f[3] = f2bf(x.w * SQK);
    f[4] = f2bf(y.x * SQK); f[5] = f2bf(y.y * SQK);
    f[6] = f2bf(y.z * SQK); f[7] = f2bf(y.w * SQK);
    qf0[dd] = f;
  }
#pragma unroll
  for (int dd = 0; dd < 4; ++dd) {
    const float* qp = Q + ((size_t)b * S + q0 + w * 64 + 32 + r32) * D + dd * 16 + hi * 8;
    float4 x = ((const float4*)qp)[0];
    float4 y = ((const float4*)qp)[1];
    bf16x8 f;
    f[0] = f2bf(x.x * SQK); f[1] = f2bf(x.y * SQK);
    f[2] = f2bf(x.z * SQK); f[3] = f2bf(x.w * SQK);
    f[4] = f2bf(y.x * SQK); f[5] = f2bf(y.y * SQK);
    f[6] = f2bf(y.z * SQK); f[7] = f2bf(y.w * SQK);
    qf1[dd] = f;
  }

  // O accumulators, NAMED (no f32x16 arrays anywhere).
  // oa{s}{dhalf}: D[row=q(16 rows)][col = d = 32*dhalf + r32]
  f32x16 oa00 = {}, oa01 = {}, oa10 = {}, oa11 = {};
  float rs0 = 0.f, rs1 = 0.f;  // per-strip lane share of rowsum[q = r32]
  const f32x16 z16c = {};      // persistent zero C-operand (never written)

  const float* Kb = K + (size_t)b * S * D;
  const float* Vb = V + (size_t)b * S * D;

  // V staging (R14, verified): wave w holds keys w*8+0..7 = 16-block (w>>1),
  // sub-half (w&1). Permuted cols: j<4 -> 4*(w&1)+j ; j>=4 -> 8+4*(w&1)+(j-4).
  const int vcb = 16 * (w >> 1) + 4 * (w & 1);

  float4 kx[2];
  float  vv[8];

  // ---- prologue: tile 0 -> buf0; tile 1 loads left in flight (R14 verbatim)
#pragma unroll
  for (int i = 0; i < 2; ++i)
    kx[i] = ((const float4*)Kb)[tid + 512 * i];
#pragma unroll
  for (int j = 0; j < 8; ++j)
    vv[j] = Vb[(w * 8 + j) * D + lane];
#pragma unroll
  for (int i = 0; i < 2; ++i) {
    int f = 4 * tid + 2048 * i;
    int row = f >> 6, col = f & 63;
    uint2 pk = { pk2(kx[i].x, kx[i].y), pk2(kx[i].z, kx[i].w) };
    *(uint2*)&ksh[0][row * 72 + col] = pk;
  }
  {
    uint2 plo = { pk2(vv[0], vv[1]), pk2(vv[2], vv[3]) };
    uint2 phi = { pk2(vv[4], vv[5]), pk2(vv[6], vv[7]) };
    *(uint2*)&vsh[0][lane * 72 + vcb]     = plo;
    *(uint2*)&vsh[0][lane * 72 + vcb + 8] = phi;
  }
#pragma unroll
  for (int i = 0; i < 2; ++i)
    kx[i] = ((const float4*)(Kb + 64 * D))[tid + 512 * i];
#pragma unroll
  for (int j = 0; j < 8; ++j)
    vv[j] = Vb[(64 + w * 8 + j) * D + lane];
  __syncthreads();

  int p = 0;
  for (int kt = 0; kt < S; kt += 64, p ^= 1) {
    // ---- stage tile kt+64 (regs from last iter) into buf p^1, then issue
    // loads for tile kt+128. buf[p^1] reads finished before last barrier.
    if (kt + 64 < S) {
#pragma unroll
      for (int i = 0; i < 2; ++i) {
        int f = 4 * tid + 2048 * i;
        int row = f >> 6, col = f & 63;
        uint2 pk = { pk2(kx[i].x, kx[i].y), pk2(kx[i].z, kx[i].w) };
        *(uint2*)&ksh[p ^ 1][row * 72 + col] = pk;
      }
      {
        uint2 plo = { pk2(vv[0], vv[1]), pk2(vv[2], vv[3]) };
        uint2 phi = { pk2(vv[4], vv[5]), pk2(vv[6], vv[7]) };
        *(uint2*)&vsh[p ^ 1][lane * 72 + vcb]     = plo;
        *(uint2*)&vsh[p ^ 1][lane * 72 + vcb + 8] = phi;
      }
      if (kt + 128 < S) {
        const float* Kg2 = Kb + (size_t)(kt + 128) * D;
        const float* Vg2 = Vb + (size_t)(kt + 128) * D;
#pragma unroll
        for (int i = 0; i < 2; ++i)
          kx[i] = ((const float4*)Kg2)[tid + 512 * i];
#pragma unroll
        for (int j = 0; j < 8; ++j)
          vv[j] = Vg2[(w * 8 + j) * D + lane];
      }
    }

    const short* kshp = ksh[p];
    const short* vshp = vsh[p];
#pragma unroll
    for (int t = 0; t < 2; ++t) {
      // K fragments (A-operand), shared by BOTH strips:
      // kf[dd] = K[key = 32t + r32][d = 16dd + 8hi + j]
      bf16x8 kf[4];
#pragma unroll
      for (int dd = 0; dd < 4; ++dd)
        kf[dd] = *(const bf16x8*)&kshp[(t * 32 + r32) * 72 + dd * 16 + hi * 8];

      // V fragments (B-operand), shared by BOTH strips:
      // vf{h}{dhalf} = V[key = 32t + 16h + perm(j) + 8hi][d = 32*dhalf + r32]
      bf16x8 vf00 = *(const bf16x8*)&vshp[r32 * 72 + t * 32 + hi * 8];
      bf16x8 vf01 = *(const bf16x8*)&vshp[(32 + r32) * 72 + t * 32 + hi * 8];
      bf16x8 vf10 = *(const bf16x8*)&vshp[r32 * 72 + t * 32 + 16 + hi * 8];
      bf16x8 vf11 = *(const bf16x8*)&vshp[(32 + r32) * 72 + t * 32 + 16 + hi * 8];

      // ---- strip0 QK (z live range #1)
      f32x16 z = __builtin_amdgcn_mfma_f32_32x32x16_bf16(kf[0], qf0[0], z16c, 0, 0, 0);
      z = __builtin_amdgcn_mfma_f32_32x32x16_bf16(kf[1], qf0[1], z, 0, 0, 0);
      z = __builtin_amdgcn_mfma_f32_32x32x16_bf16(kf[2], qf0[2], z, 0, 0, 0);
      z = __builtin_amdgcn_mfma_f32_32x32x16_bf16(kf[3], qf0[3], z, 0, 0, 0);

      // ---- strip0 softmax, both halves (pa0a/pa0b live across QK1)
      bf16x8 pa0a, pa0b;
      SM_HALF(z, 0, rs0, pa0a);
      SM_HALF(z, 8, rs0, pa0b);

      // ---- strip1 QK (z reassigned: single live range at a time)
      z = __builtin_amdgcn_mfma_f32_32x32x16_bf16(kf[0], qf1[0], z16c, 0, 0, 0);
      z = __builtin_amdgcn_mfma_f32_32x32x16_bf16(kf[1], qf1[1], z, 0, 0, 0);
      z = __builtin_amdgcn_mfma_f32_32x32x16_bf16(kf[2], qf1[2], z, 0, 0, 0);
      z = __builtin_amdgcn_mfma_f32_32x32x16_bf16(kf[3], qf1[3], z, 0, 0, 0);

      // ---- PV0 interleaved with strip1 softmax: SM1's exp2/pk2 (VALU +
      // trans pipes) hides under PV0's MFMAs (matrix pipe).
      bf16x8 pa1a, pa1b;
      oa00 = __builtin_amdgcn_mfma_f32_32x32x16_bf16(pa0a, vf00, oa00, 0, 0, 0);
      oa01 = __builtin_amdgcn_mfma_f32_32x32x16_bf16(pa0a, vf01, oa01, 0, 0, 0);
      SM_HALF(z, 0, rs1, pa1a);
      oa00 = __builtin_amdgcn_mfma_f32_32x32x16_bf16(pa0b, vf10, oa00, 0, 0, 0);
      oa01 = __builtin_amdgcn_mfma_f32_32x32x16_bf16(pa0b, vf11, oa01, 0, 0, 0);
      SM_HALF(z, 8, rs1, pa1b);

      // ---- PV1
      oa10 = __builtin_amdgcn_mfma_f32_32x32x16_bf16(pa1a, vf00, oa10, 0, 0, 0);
      oa11 = __builtin_amdgcn_mfma_f32_32x32x16_bf16(pa1a, vf01, oa11, 0, 0, 0);
      oa10 = __builtin_amdgcn_mfma_f32_32x32x16_bf16(pa1b, vf10, oa10, 0, 0, 0);
      oa11 = __builtin_amdgcn_mfma_f32_32x32x16_bf16(pa1b, vf11, oa11, 0, 0, 0);
    }
    __syncthreads();
  }

  // ---- epilogue, per strip: rowsum for q=r32 (combine hi halves), then
  // gather via one-time shfls. Row g of oa** is q-offset (g&3)+8(g>>2)+4hi.
  {
    float tot = rs0 + __shfl_xor(rs0, 32);
#pragma unroll
    for (int g = 0; g < 16; ++g) {
      int rq = (g & 3) + 8 * (g >> 2) + 4 * hi;
      float inv = 1.0f / __shfl(tot, rq);
      int q = q0 + w * 64 + rq;
      float* op = O + ((size_t)b * S + q) * D + r32;
      op[0]  = oa00[g] * inv;
      op[32] = oa01[g] * inv;
    }
  }
  {
    float tot = rs1 + __shfl_xor(rs1, 32);
#pragma unroll
    for (int g = 0; g < 16; ++g) {
      int rq = (g & 3) + 8 * (g >> 2) + 4 * hi;
      float inv = 1.0f / __shfl(tot, rq);
      int q = q0 + w * 64 + 32 + rq;
      float* op = O + ((size_t)b * S + q) * D + r32;
      op[0]  = oa10[g] * inv;
      op[32] = oa11[g] * inv;
    }
  }
}

extern "C" void kernel_launch(void* const* d_in, const int* in_sizes, int n_in,
                              void* d_out, int out_size, void* d_ws, size_t ws_size,
                              hipStream_t stream) {
  (void)in_sizes; (void)n_in; (void)out_size; (void)d_ws; (void)ws_size;
  const float* Q = (const float*)d_in[0];
  const float* K = (const float*)d_in[1];
  const float* V = (const float*)d_in[2];
  float* O = (float*)d_out;
  // grid.x = batch: linear block id = x + 64*y -> XCD = id%8 = b%8, so all
  // 4 q-blocks of a batch share one XCD (K/V L2 reuse). 256 blocks = 1/CU.
  dim3 grid(64, 2048 / 512, 1);
  dim3 block(512, 1, 1);
  hipLaunchKernelGGL(DotProductAttention_44573170598739_kernel,
                     grid, block, 0, stream, Q, K, V, O);
}